// Round 1
// baseline (364.079 us; speedup 1.0000x reference)
//
#include <hip/hip_runtime.h>
#include <hip/hip_bf16.h>
#include <stdint.h>

typedef __attribute__((ext_vector_type(4))) float f32x4;
typedef __attribute__((ext_vector_type(8))) short short8;

// ---------------- geometry ----------------
// input  x: (8,512,64,64) f32, NCHW
// conv1:  512ch 3x3 pad1 + relu -> f (bf16, NHWC: [32768 pos][512])
// heads:  1x1 convs (18 cls + 36 reg) + anchor decode
#define NB 8
#define NC 512
#define NH 64
#define NW 64
#define HP 66
#define WP 66
#define NPOS (NB*NH*NW)          // 32768
#define KTOT (NC*9)              // 4608

#define XP_ELEMS (NB*HP*WP*NC)   // 17,842,176 bf16
#define WR_ELEMS (NC*KTOT)       // 2,359,296 bf16
#define WC2_ELEMS (64*NC)        // 32,768 bf16 (54 rows used, padded to 64)

#define PROP_OFF 0
#define CLS_OFF  1179648         // 8*36864*4
#define A_PER_B  36864

__device__ __forceinline__ short bf16bits(float v) {
    __hip_bfloat16 b = __float2bfloat16(v);
    return *reinterpret_cast<short*>(&b);
}

__device__ __forceinline__ void gload16(const short* g, short* l) {
    __builtin_amdgcn_global_load_lds(
        (const __attribute__((address_space(1))) unsigned int*)g,
        (__attribute__((address_space(3))) unsigned int*)l,
        16, 0, 0);
}

// ---------------- prep 1: NCHW f32 -> padded NHWC bf16 ----------------
// grid (128 pos-blocks, 16 ci-blocks, 8 b), block (32,8)
__global__ void prep_input(const float* __restrict__ x, short* __restrict__ Xp) {
    __shared__ float tile[32][33];
    const int pb = blockIdx.x, cb = blockIdx.y, b = blockIdx.z;
    const int tx = threadIdx.x, ty = threadIdx.y;
    const float* src = x + ((size_t)(b*NC + cb*32))*4096 + pb*32;
#pragma unroll
    for (int r = 0; r < 4; ++r) {
        int cl = ty + r*8;
        tile[cl][tx] = src[(size_t)cl*4096 + tx];
    }
    __syncthreads();
#pragma unroll
    for (int r = 0; r < 4; ++r) {
        int pl = ty + r*8;
        int pos = pb*32 + pl;
        int h = pos >> 6, w = pos & 63;
        Xp[((size_t)((b*HP + h + 1)*WP) + (w + 1))*NC + cb*32 + tx] = bf16bits(tile[tx][pl]);
    }
}

// ---------------- prep 2: conv_w OIHW f32 -> Wr[co][(kh*3+kw)*512+ci] bf16 ----
__global__ void prep_w(const float* __restrict__ w, short* __restrict__ Wr) {
    int tid = blockIdx.x*256 + threadIdx.x;
    if (tid >= NC*KTOT) return;
    int o = tid / KTOT;
    int rem = tid - o*KTOT;
    int seg = rem >> 9, ci = rem & 511;
    int kh = seg/3, kw = seg - kh*3;
    Wr[tid] = bf16bits(w[(((size_t)o*NC + ci)*3 + kh)*3 + kw]);
}

// ---------------- prep 3: cls_w/reg_w -> Wc2[64][512] bf16 (rows 54..63 = 0) --
__global__ void prep_w2(const float* __restrict__ cls_w, const float* __restrict__ reg_w,
                        short* __restrict__ Wc2) {
    int tid = blockIdx.x*256 + threadIdx.x;   // 32768 total
    int row = tid >> 9, ci = tid & 511;
    float v = 0.f;
    if (row < 18)      v = cls_w[row*NC + ci];
    else if (row < 54) v = reg_w[(row-18)*NC + ci];
    Wc2[tid] = bf16bits(v);
}

// ---------------- main: implicit-GEMM conv3x3 + bias + relu ----------------
// C[p][co] : M=32768 (spatial), N=512 (co), K=4608
// 128x128 tile, BK=32, 4 waves (2x2 of 64x64), 16x16x32 MFMA, m97 structure.
__launch_bounds__(256)
__global__ void conv3x3_gemm(const short* __restrict__ Xp, const short* __restrict__ Wr,
                             const float* __restrict__ bias, short* __restrict__ f) {
    __shared__ short As[128*32];
    __shared__ short Bs[128*32];
    const int tid  = threadIdx.x;
    const int lane = tid & 63, wv = tid >> 6;
    const int pbase  = blockIdx.x * 128;
    const int cobase = blockIdx.y * 128;

    // staging: per issue q in {0,1}: LDS row = q*64 + wv*16 + lane/4, k = (lane&3)*8
    const int srow = wv*16 + (lane >> 2);
    const int koff = (lane & 3) * 8;
    int aoff[2], boff[2];
#pragma unroll
    for (int q = 0; q < 2; ++q) {
        int p = pbase + srow + q*64;
        int b = p >> 12, h = (p >> 6) & 63, w = p & 63;
        aoff[q] = ((b*HP + h)*WP + w)*NC + koff;           // dh,dw added per segment
        boff[q] = (cobase + srow + q*64)*KTOT + koff;
    }
    short* ldsA = &As[wv*512];
    short* ldsB = &Bs[wv*512];

    f32x4 acc[4][4];
#pragma unroll
    for (int i = 0; i < 4; ++i)
#pragma unroll
        for (int j = 0; j < 4; ++j)
            acc[i][j] = (f32x4){0.f, 0.f, 0.f, 0.f};

    const int wm = wv >> 1, wn = wv & 1;
    const int fro = lane & 15;
    const int fko = (lane >> 4) * 8;

    for (int seg = 0; seg < 9; ++seg) {
        const int dh = seg/3, dw = seg - dh*3;
        const int segoff = (dh*WP + dw)*NC;
        const int kb = seg*NC;
        for (int kk = 0; kk < NC; kk += 32) {
            __syncthreads();
#pragma unroll
            for (int q = 0; q < 2; ++q) {
                gload16(Xp + aoff[q] + segoff + kk, ldsA + q*2048);
                gload16(Wr + boff[q] + kb + kk,     ldsB + q*2048);
            }
            __syncthreads();
            short8 af[4], bq[4];
#pragma unroll
            for (int i = 0; i < 4; ++i)
                af[i] = *(const short8*)&As[(wm*64 + i*16 + fro)*32 + fko];
#pragma unroll
            for (int j = 0; j < 4; ++j)
                bq[j] = *(const short8*)&Bs[(wn*64 + j*16 + fro)*32 + fko];
#pragma unroll
            for (int i = 0; i < 4; ++i)
#pragma unroll
                for (int j = 0; j < 4; ++j)
                    acc[i][j] = __builtin_amdgcn_mfma_f32_16x16x32_bf16(af[i], bq[j], acc[i][j], 0, 0, 0);
        }
    }

    // epilogue: D col = lane&15, row = (lane>>4)*4 + r
    const int crow0 = (lane >> 4) * 4;
    const int ccol  = lane & 15;
#pragma unroll
    for (int j = 0; j < 4; ++j) {
        const int co = cobase + wn*64 + j*16 + ccol;
        const float bb = bias[co];
#pragma unroll
        for (int i = 0; i < 4; ++i) {
#pragma unroll
            for (int r = 0; r < 4; ++r) {
                int p = pbase + wm*64 + i*16 + crow0 + r;
                float v = acc[i][j][r] + bb;
                v = v > 0.f ? v : 0.f;
                f[(size_t)p*NC + co] = bf16bits(v);
            }
        }
    }
}

// ---------------- stage 2: 1x1 convs + anchor decode ----------------
// per block: 64 positions, 4 waves (16 pos each), N=64 (54 used), K=512
__device__ const float AW_T[9] = {
    181.01933598375618f, 362.03867196751236f, 724.0773439350247f,
    128.f, 256.f, 512.f,
    90.50966799187809f, 181.01933598375618f, 362.03867196751236f };
__device__ const float AH_T[9] = {
    90.50966799187809f, 181.01933598375618f, 362.03867196751236f,
    128.f, 256.f, 512.f,
    181.01933598375618f, 362.03867196751236f, 724.0773439350247f };

__launch_bounds__(256)
__global__ void head_decode(const short* __restrict__ f, const short* __restrict__ Wc2,
                            const float* __restrict__ cls_b, const float* __restrict__ reg_b,
                            const int* __restrict__ img, float* __restrict__ out) {
    __shared__ float sm[64*65];
    const int tid = threadIdx.x, lane = tid & 63, wv = tid >> 6;
    const int p0 = blockIdx.x * 64;
    const int prow = lane & 15;
    const int kgrp = (lane >> 4) * 8;

    f32x4 acc[4];
#pragma unroll
    for (int j = 0; j < 4; ++j) acc[j] = (f32x4){0.f, 0.f, 0.f, 0.f};

    const short* arow = f + (size_t)(p0 + wv*16 + prow)*NC + kgrp;
#pragma unroll
    for (int k0 = 0; k0 < NC; k0 += 32) {
        short8 a = *(const short8*)(arow + k0);
#pragma unroll
        for (int j = 0; j < 4; ++j) {
            short8 b = *(const short8*)(Wc2 + (size_t)(j*16 + prow)*NC + k0 + kgrp);
            acc[j] = __builtin_amdgcn_mfma_f32_16x16x32_bf16(a, b, acc[j], 0, 0, 0);
        }
    }
    const int crow0 = wv*16 + (lane >> 4)*4;
#pragma unroll
    for (int j = 0; j < 4; ++j)
#pragma unroll
        for (int r = 0; r < 4; ++r)
            sm[(crow0 + r)*65 + j*16 + (lane & 15)] = acc[j][r];
    __syncthreads();

    for (int item = tid; item < 64*9; item += 256) {
        int pl = item / 9, a = item - pl*9;
        int p = p0 + pl;
        int b = p >> 12, h = (p >> 6) & 63, w = p & 63;
        float c0 = sm[pl*65 + a*2 + 0] + cls_b[a*2 + 0];
        float c1 = sm[pl*65 + a*2 + 1] + cls_b[a*2 + 1];
        float r0 = sm[pl*65 + 18 + a*4 + 0] + reg_b[a*4 + 0];
        float r1 = sm[pl*65 + 18 + a*4 + 1] + reg_b[a*4 + 1];
        float r2 = sm[pl*65 + 18 + a*4 + 2] + reg_b[a*4 + 2];
        float r3 = sm[pl*65 + 18 + a*4 + 3] + reg_b[a*4 + 3];
        float aw = AW_T[a], ah = AH_T[a];
        float ax = 8.f + 16.f*w, ay = 8.f + 16.f*h;
        float px = ax + r0*aw,  py = ay + r1*ah;
        float pw = aw*__expf(r2), ph = ah*__expf(r3);
        float imw = (float)img[b*2 + 0], imh = (float)img[b*2 + 1];
        float x1 = fminf(fmaxf(px - 0.5f*pw, 0.f), imw);
        float y1 = fminf(fmaxf(py - 0.5f*ph, 0.f), imh);
        float x2 = fminf(fmaxf(px + 0.5f*pw, 0.f), imw);
        float y2 = fminf(fmaxf(py + 0.5f*ph, 0.f), imh);
        int ag = (h*64 + w)*9 + a;
        float4* prop = (float4*)(out + PROP_OFF + ((size_t)b*A_PER_B + ag)*4);
        *prop = make_float4(x1, y1, x2, y2);
        float2* cs = (float2*)(out + CLS_OFF + ((size_t)b*A_PER_B + ag)*2);
        *cs = make_float2(c0, c1);
    }
}

extern "C" void kernel_launch(void* const* d_in, const int* in_sizes, int n_in,
                              void* d_out, int out_size, void* d_ws, size_t ws_size,
                              hipStream_t stream) {
    const float* x      = (const float*)d_in[0];
    const int*   img    = (const int*)  d_in[1];
    const float* conv_w = (const float*)d_in[2];
    const float* conv_b = (const float*)d_in[3];
    const float* cls_w  = (const float*)d_in[4];
    const float* cls_b  = (const float*)d_in[5];
    const float* reg_w  = (const float*)d_in[6];
    const float* reg_b  = (const float*)d_in[7];
    float* out = (float*)d_out;

    short* Xp  = (short*)d_ws;
    short* Wr  = Xp  + XP_ELEMS;
    short* Wc2 = Wr  + WR_ELEMS;
    short* f   = Wc2 + WC2_ELEMS;

    // zero: padded input borders + anchors_ignore (and all of d_out)
    hipMemsetAsync(Xp, 0, (size_t)XP_ELEMS*2, stream);
    hipMemsetAsync(d_out, 0, (size_t)out_size*4, stream);

    prep_input<<<dim3(128,16,8), dim3(32,8), 0, stream>>>(x, Xp);
    prep_w <<<9216, 256, 0, stream>>>(conv_w, Wr);
    prep_w2<<<128, 256, 0, stream>>>(cls_w, reg_w, Wc2);
    conv3x3_gemm<<<dim3(NPOS/128, 4), 256, 0, stream>>>(Xp, Wr, conv_b, f);
    head_decode <<<NPOS/64, 256, 0, stream>>>(f, Wc2, cls_b, reg_b, img, out);
}

// Round 2
// 282.969 us; speedup vs baseline: 1.2866x; 1.2866x over previous
//
#include <hip/hip_runtime.h>
#include <hip/hip_bf16.h>
#include <stdint.h>

typedef __attribute__((ext_vector_type(4))) float f32x4;
typedef __attribute__((ext_vector_type(8))) short short8;

// ---------------- geometry ----------------
#define NB 8
#define NC 512
#define HP 66
#define WP 66
#define NPOS 32768
#define KTOT 4608
#define NKT 72           // K-tiles of 64

#define XP_ELEMS (NB*HP*WP*NC)
#define WR_ELEMS (NC*KTOT)
#define WC2_ELEMS (64*NC)
#define PROP_OFF 0
#define CLS_OFF  1179648
#define A_PER_B  36864

__device__ __forceinline__ short bf16bits(float v) {
    __hip_bfloat16 b = __float2bfloat16(v);
    return *reinterpret_cast<short*>(&b);
}
__device__ __forceinline__ void gload16(const short* g, short* l) {
    __builtin_amdgcn_global_load_lds(
        (const __attribute__((address_space(1))) unsigned int*)g,
        (__attribute__((address_space(3))) unsigned int*)l, 16, 0, 0);
}
#define BARRIER() asm volatile("s_barrier" ::: "memory")
#define VMCNT4()  asm volatile("s_waitcnt vmcnt(4)" ::: "memory")
#define VMCNT0()  asm volatile("s_waitcnt vmcnt(0)" ::: "memory")

// ---------------- prep 1: NCHW f32 -> padded NHWC bf16 (16B writes) --------
// grid (64 h-rows, 8 ch-blocks, 8 b), block 256
__global__ void prep_input(const float* __restrict__ x, short* __restrict__ Xp) {
    __shared__ float t[64][65];
    const int pb = blockIdx.x, cb = blockIdx.y, b = blockIdx.z;
    const int tid = threadIdx.x;
    const int tx = tid & 63, ty = tid >> 6;
    const float* src = x + ((size_t)(b*NC + cb*64))*4096 + pb*64;
#pragma unroll
    for (int r = 0; r < 16; ++r) {
        int ch = ty + r*4;
        t[ch][tx] = src[(size_t)ch*4096 + tx];
    }
    __syncthreads();
#pragma unroll
    for (int rr = 0; rr < 2; ++rr) {
        int item = tid + rr*256;
        int pl = item >> 3, ck = item & 7;
        short8 v;
#pragma unroll
        for (int e = 0; e < 8; ++e) v[e] = bf16bits(t[ck*8+e][pl]);
        *(short8*)&Xp[((size_t)((b*HP + pb + 1)*WP) + (pl + 1))*NC + cb*64 + ck*8] = v;
    }
}

// ---------------- prep 2: conv_w OIHW f32 -> Wr[co][k*512+ci], LDS-staged ---
__global__ void prep_w(const float* __restrict__ w, short* __restrict__ Wr) {
    __shared__ float t[4608];
    const int o = blockIdx.x;
    const int tid = threadIdx.x;
    const float* src = w + (size_t)o*4608;
    for (int i = tid; i < 4608; i += 256) t[i] = src[i];
    __syncthreads();
#pragma unroll
    for (int k = 0; k < 9; ++k) {
#pragma unroll
        for (int c = 0; c < 2; ++c) {
            int ci = tid + c*256;
            Wr[(size_t)o*4608 + k*512 + ci] = bf16bits(t[ci*9 + k]);
        }
    }
}

// ---------------- prep 3: cls_w/reg_w -> Wc2[64][512] bf16 ------------------
__global__ void prep_w2(const float* __restrict__ cls_w, const float* __restrict__ reg_w,
                        short* __restrict__ Wc2) {
    int tid = blockIdx.x*256 + threadIdx.x;
    int row = tid >> 9, ci = tid & 511;
    float v = 0.f;
    if (row < 18)      v = cls_w[row*NC + ci];
    else if (row < 54) v = reg_w[(row-18)*NC + ci];
    Wc2[tid] = bf16bits(v);
}

// ---------------- main: 256^2-tile 8-phase implicit-GEMM conv3x3 ------------
// C[p][co]: M=32768, N=512, K=4608. BM=BN=256, BK=64, 8 waves (2x4).
// LDS 128KB: buf{0,1} x [A half0, A half1, B half0, B half1] of [128][64] bf16.
// Swizzle: LDS slot (row,g) holds k-group g^(row&7); applied on stage source
// AND ds_read (both-sides, rule #21). Counted vmcnt(4) at ph4/ph8 (T4).
__launch_bounds__(512, 2)
__global__ void conv3x3_gemm(const short* __restrict__ Xp, const short* __restrict__ Wr,
                             const float* __restrict__ bias, short* __restrict__ f) {
    extern __shared__ short lds[];
    const int tid = threadIdx.x;
    const int lane = tid & 63, wv = tid >> 6;
    const int bid = blockIdx.x;
    const int wg = (bid & 7) * 32 + (bid >> 3);       // XCD swizzle (256%8==0)
    const int pbase  = (wg >> 1) * 256;
    const int cobase = (wg & 1) * 256;
    const int wm = wv >> 2, wn = wv & 3;

    // staging precompute: thread covers row (tid>>3), slot (tid&7) of a half
    const int g_data = (tid & 7) ^ ((tid >> 3) & 7);  // pre-swizzled k-group
    int abase[4], bbase[4];
#pragma unroll
    for (int q = 0; q < 4; ++q) {
        int p = pbase + q*64 + (tid >> 3);
        int b = p >> 12, h = (p >> 6) & 63, w = p & 63;
        abase[q] = ((b*HP + h)*WP + w)*NC + g_data*8;
        bbase[q] = (cobase + q*64 + (tid >> 3))*KTOT + g_data*8;
    }
    const int stoff = tid*8;

    // read-side precompute
    const int l15 = lane & 15, l4 = lane >> 4, l7 = lane & 7;
    const int kidx0 = (l4 ^ l7) * 8;
    const int kidx1 = ((4 + l4) ^ l7) * 8;
    const int Aroff = wm*8192 + l15*64;
    const int Broff = 16384 + (wn>>1)*8192 + (wn&1)*4096 + l15*64;

    auto stageA = [&](int t, int hh) {
        int seg = t >> 3;
        int dh = seg / 3, dw = seg - dh*3;
        int off = (dh*WP + dw)*NC + (t & 7)*64;
        short* dst = lds + (t & 1)*32768 + hh*8192 + stoff;
        gload16(Xp + abase[hh*2+0] + off, dst);
        gload16(Xp + abase[hh*2+1] + off, dst + 4096);
    };
    auto stageB = [&](int t, int hh) {
        int off = t * 64;
        short* dst = lds + (t & 1)*32768 + 16384 + hh*8192 + stoff;
        gload16(Wr + bbase[hh*2+0] + off, dst);
        gload16(Wr + bbase[hh*2+1] + off, dst + 4096);
    };

    f32x4 acc[8][4];
#pragma unroll
    for (int i = 0; i < 8; ++i)
#pragma unroll
        for (int j = 0; j < 4; ++j) acc[i][j] = (f32x4){0.f,0.f,0.f,0.f};

    short8 af[2][2], bfr[4][2];
    auto readA = [&](int bufb, int i2) {
        const short* Ab = lds + bufb*32768 + Aroff;
#pragma unroll
        for (int ii = 0; ii < 2; ++ii) {
            af[ii][0] = *(const short8*)(Ab + (i2+ii)*1024 + kidx0);
            af[ii][1] = *(const short8*)(Ab + (i2+ii)*1024 + kidx1);
        }
    };
    auto readB = [&](int bufb) {
        const short* Bb = lds + bufb*32768 + Broff;
#pragma unroll
        for (int j = 0; j < 4; ++j) {
            bfr[j][0] = *(const short8*)(Bb + j*1024 + kidx0);
            bfr[j][1] = *(const short8*)(Bb + j*1024 + kidx1);
        }
    };
    auto mfmaQ = [&](int i2) {
        __builtin_amdgcn_s_setprio(1);
#pragma unroll
        for (int kk = 0; kk < 2; ++kk)
#pragma unroll
            for (int ii = 0; ii < 2; ++ii)
#pragma unroll
                for (int j = 0; j < 4; ++j)
                    acc[i2+ii][j] = __builtin_amdgcn_mfma_f32_16x16x32_bf16(
                        af[ii][kk], bfr[j][kk], acc[i2+ii][j], 0, 0, 0);
        __builtin_amdgcn_s_setprio(0);
    };

    // prologue: B(0),A(0) -> buf0; B(1) -> buf1; drain through A(0)
    stageB(0,0); stageB(0,1); stageA(0,0); stageA(0,1); stageB(1,0); stageB(1,1);
    VMCNT4(); BARRIER();

    for (int it = 0; it < 36; ++it) {
        const int t1 = 2*it+1, t2 = 2*it+2, t3 = 2*it+3;
        const bool s2 = (t2 < NKT), s3 = (t3 < NKT);
        // ph1: tile t0 (buf0)
        readB(0); readA(0, 0);
        stageA(t1, 0);
        BARRIER(); mfmaQ(0); BARRIER();
        // ph2
        readA(0, 2);
        stageA(t1, 1);
        BARRIER(); mfmaQ(2); BARRIER();
        // ph3
        readA(0, 4);
        if (s2) stageB(t2, 0);
        BARRIER(); mfmaQ(4); BARRIER();
        // ph4
        readA(0, 6);
        if (s2) stageB(t2, 1);
        BARRIER(); mfmaQ(6);
        if (s2) { VMCNT4(); } else { VMCNT0(); }
        BARRIER();
        // ph5: tile t1 (buf1)
        readB(1); readA(1, 0);
        if (s2) stageA(t2, 0);
        BARRIER(); mfmaQ(0); BARRIER();
        // ph6
        readA(1, 2);
        if (s2) stageA(t2, 1);
        BARRIER(); mfmaQ(2); BARRIER();
        // ph7
        readA(1, 4);
        if (s3) stageB(t3, 0);
        BARRIER(); mfmaQ(4); BARRIER();
        // ph8
        readA(1, 6);
        if (s3) stageB(t3, 1);
        BARRIER(); mfmaQ(6);
        if (s3) { VMCNT4(); } else { VMCNT0(); }
        BARRIER();
    }

    // epilogue: bias + relu + bf16 store. D col=lane&15, row=(lane>>4)*4+r
#pragma unroll
    for (int j = 0; j < 4; ++j) {
        const int col = cobase + wn*64 + j*16 + l15;
        const float bb = bias[col];
#pragma unroll
        for (int i = 0; i < 8; ++i) {
#pragma unroll
            for (int r = 0; r < 4; ++r) {
                int row = pbase + wm*128 + i*16 + l4*4 + r;
                float v = acc[i][j][r] + bb;
                v = v > 0.f ? v : 0.f;
                f[(size_t)row*NC + col] = bf16bits(v);
            }
        }
    }
}

// ---------------- stage 2: 1x1 convs + anchor decode ----------------
__device__ const float AW_T[9] = {
    181.01933598375618f, 362.03867196751236f, 724.0773439350247f,
    128.f, 256.f, 512.f,
    90.50966799187809f, 181.01933598375618f, 362.03867196751236f };
__device__ const float AH_T[9] = {
    90.50966799187809f, 181.01933598375618f, 362.03867196751236f,
    128.f, 256.f, 512.f,
    181.01933598375618f, 362.03867196751236f, 724.0773439350247f };

__launch_bounds__(256)
__global__ void head_decode(const short* __restrict__ f, const short* __restrict__ Wc2,
                            const float* __restrict__ cls_b, const float* __restrict__ reg_b,
                            const int* __restrict__ img, float* __restrict__ out) {
    __shared__ float sm[64*65];
    const int tid = threadIdx.x, lane = tid & 63, wv = tid >> 6;
    const int p0 = blockIdx.x * 64;
    const int prow = lane & 15;
    const int kgrp = (lane >> 4) * 8;

    f32x4 acc[4];
#pragma unroll
    for (int j = 0; j < 4; ++j) acc[j] = (f32x4){0.f, 0.f, 0.f, 0.f};

    const short* arow = f + (size_t)(p0 + wv*16 + prow)*NC + kgrp;
#pragma unroll
    for (int k0 = 0; k0 < NC; k0 += 32) {
        short8 a = *(const short8*)(arow + k0);
#pragma unroll
        for (int j = 0; j < 4; ++j) {
            short8 b = *(const short8*)(Wc2 + (size_t)(j*16 + prow)*NC + k0 + kgrp);
            acc[j] = __builtin_amdgcn_mfma_f32_16x16x32_bf16(a, b, acc[j], 0, 0, 0);
        }
    }
    const int crow0 = wv*16 + (lane >> 4)*4;
#pragma unroll
    for (int j = 0; j < 4; ++j)
#pragma unroll
        for (int r = 0; r < 4; ++r)
            sm[(crow0 + r)*65 + j*16 + (lane & 15)] = acc[j][r];
    __syncthreads();

    for (int item = tid; item < 64*9; item += 256) {
        int pl = item / 9, a = item - pl*9;
        int p = p0 + pl;
        int b = p >> 12, h = (p >> 6) & 63, w = p & 63;
        float c0 = sm[pl*65 + a*2 + 0] + cls_b[a*2 + 0];
        float c1 = sm[pl*65 + a*2 + 1] + cls_b[a*2 + 1];
        float r0 = sm[pl*65 + 18 + a*4 + 0] + reg_b[a*4 + 0];
        float r1 = sm[pl*65 + 18 + a*4 + 1] + reg_b[a*4 + 1];
        float r2 = sm[pl*65 + 18 + a*4 + 2] + reg_b[a*4 + 2];
        float r3 = sm[pl*65 + 18 + a*4 + 3] + reg_b[a*4 + 3];
        float aw = AW_T[a], ah = AH_T[a];
        float ax = 8.f + 16.f*w, ay = 8.f + 16.f*h;
        float px = ax + r0*aw,  py = ay + r1*ah;
        float pw = aw*__expf(r2), ph = ah*__expf(r3);
        float imw = (float)img[b*2 + 0], imh = (float)img[b*2 + 1];
        float x1 = fminf(fmaxf(px - 0.5f*pw, 0.f), imw);
        float y1 = fminf(fmaxf(py - 0.5f*ph, 0.f), imh);
        float x2 = fminf(fmaxf(px + 0.5f*pw, 0.f), imw);
        float y2 = fminf(fmaxf(py + 0.5f*ph, 0.f), imh);
        int ag = (h*64 + w)*9 + a;
        float4* prop = (float4*)(out + PROP_OFF + ((size_t)b*A_PER_B + ag)*4);
        *prop = make_float4(x1, y1, x2, y2);
        float2* cs = (float2*)(out + CLS_OFF + ((size_t)b*A_PER_B + ag)*2);
        *cs = make_float2(c0, c1);
    }
}

extern "C" void kernel_launch(void* const* d_in, const int* in_sizes, int n_in,
                              void* d_out, int out_size, void* d_ws, size_t ws_size,
                              hipStream_t stream) {
    const float* x      = (const float*)d_in[0];
    const int*   img    = (const int*)  d_in[1];
    const float* conv_w = (const float*)d_in[2];
    const float* conv_b = (const float*)d_in[3];
    const float* cls_w  = (const float*)d_in[4];
    const float* cls_b  = (const float*)d_in[5];
    const float* reg_w  = (const float*)d_in[6];
    const float* reg_b  = (const float*)d_in[7];
    float* out = (float*)d_out;

    short* Xp  = (short*)d_ws;
    short* Wr  = Xp  + XP_ELEMS;
    short* Wc2 = Wr  + WR_ELEMS;
    short* f   = Wc2 + WC2_ELEMS;

    hipMemsetAsync(Xp, 0, (size_t)XP_ELEMS*2, stream);
    hipMemsetAsync(d_out, 0, (size_t)out_size*4, stream);

    prep_input<<<dim3(64,8,8), 256, 0, stream>>>(x, Xp);
    prep_w <<<512, 256, 0, stream>>>(conv_w, Wr);
    prep_w2<<<128, 256, 0, stream>>>(cls_w, reg_w, Wc2);

    hipFuncSetAttribute((const void*)conv3x3_gemm,
                        hipFuncAttributeMaxDynamicSharedMemorySize, 131072);
    conv3x3_gemm<<<256, 512, 131072, stream>>>(Xp, Wr, conv_b, f);
    head_decode <<<NPOS/64, 256, 0, stream>>>(f, Wc2, cls_b, reg_b, img, out);
}

// Round 3
// 265.913 us; speedup vs baseline: 1.3692x; 1.0641x over previous
//
#include <hip/hip_runtime.h>
#include <hip/hip_bf16.h>
#include <stdint.h>

typedef __attribute__((ext_vector_type(4))) float f32x4;
typedef __attribute__((ext_vector_type(8))) short short8;

// ---------------- geometry ----------------
#define NB 8
#define NC 512
#define HP 66
#define WP 66
#define NPOS 32768
#define KTOT 4608
#define NT 144            // K-tiles of 32

#define XP_ELEMS (NB*HP*WP*NC)
#define WR_ELEMS (NC*KTOT)
#define WC2_ELEMS (64*NC)
#define PROP_OFF 0
#define CLS_OFF  1179648
#define ANCH_OFF 1769472
#define A_PER_B  36864

__device__ __forceinline__ short bf16bits(float v) {
    __hip_bfloat16 b = __float2bfloat16(v);
    return *reinterpret_cast<short*>(&b);
}
__device__ __forceinline__ void gload16(const short* g, short* l) {
    __builtin_amdgcn_global_load_lds(
        (const __attribute__((address_space(1))) unsigned int*)g,
        (__attribute__((address_space(3))) unsigned int*)l, 16, 0, 0);
}
#define BARRIER() asm volatile("s_barrier" ::: "memory")
#define VMCNT4()  asm volatile("s_waitcnt vmcnt(4)" ::: "memory")
#define VMCNT0()  asm volatile("s_waitcnt vmcnt(0)" ::: "memory")

// ---------------- prep 1: NCHW f32 -> padded NHWC bf16 (16B writes) --------
__global__ void prep_input(const float* __restrict__ x, short* __restrict__ Xp) {
    __shared__ float t[64][65];
    const int pb = blockIdx.x, cb = blockIdx.y, b = blockIdx.z;
    const int tid = threadIdx.x;
    const int tx = tid & 63, ty = tid >> 6;
    const float* src = x + ((size_t)(b*NC + cb*64))*4096 + pb*64;
#pragma unroll
    for (int r = 0; r < 16; ++r) {
        int ch = ty + r*4;
        t[ch][tx] = src[(size_t)ch*4096 + tx];
    }
    __syncthreads();
#pragma unroll
    for (int rr = 0; rr < 2; ++rr) {
        int item = tid + rr*256;
        int pl = item >> 3, ck = item & 7;
        short8 v;
#pragma unroll
        for (int e = 0; e < 8; ++e) v[e] = bf16bits(t[ck*8+e][pl]);
        *(short8*)&Xp[((size_t)((b*HP + pb + 1)*WP) + (pl + 1))*NC + cb*64 + ck*8] = v;
    }
}

// ---------------- prep 2: conv_w OIHW f32 -> Wr[co][k*512+ci], LDS-staged ---
__global__ void prep_w(const float* __restrict__ w, short* __restrict__ Wr) {
    __shared__ float t[4608];
    const int o = blockIdx.x;
    const int tid = threadIdx.x;
    const float* src = w + (size_t)o*4608;
    for (int i = tid; i < 4608; i += 256) t[i] = src[i];
    __syncthreads();
#pragma unroll
    for (int k = 0; k < 9; ++k) {
#pragma unroll
        for (int c = 0; c < 2; ++c) {
            int ci = tid + c*256;
            Wr[(size_t)o*4608 + k*512 + ci] = bf16bits(t[ci*9 + k]);
        }
    }
}

// ---------------- prep_misc: Wc2 pack + Xp border zeros + anchors zeros -----
// grid 936: [0,128) Wc2; [128,648) border; [648,936) anchors
__global__ void prep_misc(const float* __restrict__ cls_w, const float* __restrict__ reg_w,
                          short* __restrict__ Wc2, short* __restrict__ Xp,
                          float* __restrict__ out) {
    const int bid = blockIdx.x, tid = threadIdx.x;
    if (bid < 128) {
        int t = bid*256 + tid;
        int row = t >> 9, ci = t & 511;
        float v = 0.f;
        if (row < 18)      v = cls_w[row*NC + ci];
        else if (row < 54) v = reg_w[(row-18)*NC + ci];
        Wc2[t] = bf16bits(v);
    } else if (bid < 648) {
        int idx = (bid-128)*256 + tid;           // < 133120
        int b = idx / 16640;
        int rem = idx - b*16640;
        int r = rem >> 6, g = rem & 63;
        int h, w;
        if      (r < 66)  { h = 0;       w = r; }
        else if (r < 132) { h = 65;      w = r - 66; }
        else if (r < 196) { h = r - 131; w = 0; }
        else              { h = r - 195; w = 65; }
        short8 z = (short8){0,0,0,0,0,0,0,0};
        *(short8*)&Xp[((size_t)((b*HP + h)*WP) + w)*NC + g*8] = z;
    } else {
        int idx = (bid-648)*256 + tid;           // < 73728 float4s
        ((float4*)(out + ANCH_OFF))[idx] = make_float4(0.f,0.f,0.f,0.f);
    }
}

// ---------------- fused: conv3x3 GEMM + 1x1 heads + anchor decode -----------
// C[p][co]: M=32768, N=512, K=4608. BM=128, BN=512, BK=32, 8 waves (2M x 4N).
// LDS: A dbuf 2x8KB @0, B tribuf 3x32KB @16KB (=112KB). Epilogue reuses all
// 128KB as f_tile[128][512] bf16 (XOR-swizzled), then sm[128][65] f32.
__device__ const float AW_T[9] = {
    181.01933598375618f, 362.03867196751236f, 724.0773439350247f,
    128.f, 256.f, 512.f,
    90.50966799187809f, 181.01933598375618f, 362.03867196751236f };
__device__ const float AH_T[9] = {
    90.50966799187809f, 181.01933598375618f, 362.03867196751236f,
    128.f, 256.f, 512.f,
    181.01933598375618f, 362.03867196751236f, 724.0773439350247f };

__launch_bounds__(512, 2)
__global__ void conv_fused(const short* __restrict__ Xp, const short* __restrict__ Wr,
                           const float* __restrict__ bias, const short* __restrict__ Wc2,
                           const float* __restrict__ cls_b, const float* __restrict__ reg_b,
                           const int* __restrict__ img, float* __restrict__ out) {
    extern __shared__ short lds[];
    short* Ab0 = lds;            short* Ab1 = lds + 4096;
    short* Bb0 = lds + 8192;     short* Bb1 = lds + 8192 + 16384;
    short* Bb2 = lds + 8192 + 32768;
    short* ABUF[2] = {Ab0, Ab1};
    short* BBUF[3] = {Bb0, Bb1, Bb2};

    const int tid = threadIdx.x;
    const int lane = tid & 63, wv = tid >> 6;
    const int bid = blockIdx.x;
    const int wg = (bid & 7) * 32 + (bid >> 3);   // XCD swizzle (256 blocks)
    const int pbase = wg * 128;
    const int wm = wv >> 2, wn = wv & 3;
    const int l15 = lane & 15, lg = lane >> 4;

    // ---- staging precompute: thread covers (row = tid>>2, slot s = tid&3)
    const int G = ((tid & 3) - (tid >> 3)) & 3;   // source k-group for slot
    int aoff;
    {
        int p = pbase + (tid >> 2);
        int b = p >> 12, h = (p >> 6) & 63, w = p & 63;
        aoff = ((b*HP + h)*WP + w)*NC + G*8;
    }
    const int boff = (tid >> 2)*KTOT + G*8;
    const int sdst = tid*8;

    // ---- read-side: sigma swizzle (2-way max per 16-lane group)
    const int sigma = (((lg + ((l15 >> 1) & 3)) & 3)) * 8;

    f32x4 acc[4][8];
#pragma unroll
    for (int i = 0; i < 4; ++i)
#pragma unroll
        for (int j = 0; j < 8; ++j) acc[i][j] = (f32x4){0.f,0.f,0.f,0.f};

    short8 af_[4], bf_[8];

    auto stageA = [&](int t, short* dst) {
        int seg = t >> 4;
        int dh = seg/3, dw = seg - dh*3;
        gload16(Xp + aoff + (dh*WP + dw)*NC + (t & 15)*32, dst + sdst);
    };
    auto stageB2 = [&](int t, short* dst, int q0) {
#pragma unroll
        for (int q = q0; q < q0+2; ++q)
            gload16(Wr + boff + q*128*KTOT + t*32, dst + q*4096 + sdst);
    };
    auto phA = [&](short* Ar, short* Br, bool sA, short* Aw, bool sB, short* Bw, int t) {
#pragma unroll
        for (int j = 0; j < 8; ++j)
            bf_[j] = *(const short8*)(Br + (wn*128 + j*16 + l15)*32 + sigma);
#pragma unroll
        for (int ii = 0; ii < 2; ++ii)
            af_[ii] = *(const short8*)(Ar + (wm*64 + ii*16 + l15)*32 + sigma);
        if (sA) stageA(t+1, Aw);
        if (sB) stageB2(t+2, Bw, 0);
        BARRIER();
        __builtin_amdgcn_s_setprio(1);
#pragma unroll
        for (int ii = 0; ii < 2; ++ii)
#pragma unroll
            for (int j = 0; j < 8; ++j)
                acc[ii][j] = __builtin_amdgcn_mfma_f32_16x16x32_bf16(
                    af_[ii], bf_[j], acc[ii][j], 0, 0, 0);
        __builtin_amdgcn_s_setprio(0);
        BARRIER();
    };
    auto phB = [&](short* Ar, bool sB, short* Bw, int t, int vm) {
#pragma unroll
        for (int ii = 2; ii < 4; ++ii)
            af_[ii] = *(const short8*)(Ar + (wm*64 + ii*16 + l15)*32 + sigma);
        if (sB) stageB2(t+2, Bw, 2);
        BARRIER();
        __builtin_amdgcn_s_setprio(1);
#pragma unroll
        for (int ii = 2; ii < 4; ++ii)
#pragma unroll
            for (int j = 0; j < 8; ++j)
                acc[ii][j] = __builtin_amdgcn_mfma_f32_16x16x32_bf16(
                    af_[ii], bf_[j], acc[ii][j], 0, 0, 0);
        __builtin_amdgcn_s_setprio(0);
        if (vm == 4) { VMCNT4(); } else if (vm == 0) { VMCNT0(); }
        BARRIER();
    };

    // ---- prologue: B(0) x4, A(0), B(1) x4 -> vmcnt(4) leaves B(1) in flight
    stageB2(0, Bb0, 0); stageB2(0, Bb0, 2);
    stageA(0, Ab0);
    stageB2(1, Bb1, 0); stageB2(1, Bb1, 2);
    VMCNT4(); BARRIER();

    // ---- main loop: tiles 0..137 (23 x 6), steady vmcnt(4)
#pragma unroll 1
    for (int itt = 0; itt < 23; ++itt) {
        const int t0 = itt*6;
#pragma unroll
        for (int c = 0; c < 6; ++c) {
            const int t = t0 + c;
            phA(ABUF[c&1], BBUF[c%3], true, ABUF[(c+1)&1], true, BBUF[(c+2)%3], t);
            phB(ABUF[c&1], true, BBUF[(c+2)%3], t, 4);
        }
    }
    // ---- tail: tiles 138..143 (same buffer pattern; 138%6==0)
    {
#pragma unroll
        for (int c = 0; c < 6; ++c) {
            const int t = 138 + c;
            const bool sA = (c < 5), sB = (c < 4);
            const int vm = (c < 4) ? 4 : (c == 4 ? 0 : -1);
            phA(ABUF[c&1], BBUF[c%3], sA, ABUF[(c+1)&1], sB, BBUF[(c+2)%3], t);
            phB(ABUF[c&1], sB, BBUF[(c+2)%3], t, vm);
        }
    }

    // ---- epilogue 1: bias+relu, write f_tile[128][512] bf16 (swizzled)
    // D frag: col = l15 (N), row = lg*4 + r (M)
#pragma unroll
    for (int j = 0; j < 8; ++j) {
        const int co = wn*128 + j*16 + l15;
        const float bb = bias[co];
        const int g64 = co >> 3, e = co & 7;
#pragma unroll
        for (int i = 0; i < 4; ++i) {
#pragma unroll
            for (int r = 0; r < 4; ++r) {
                const int prow = wm*64 + i*16 + lg*4 + r;
                float v = acc[i][j][r] + bb;
                v = v > 0.f ? v : 0.f;
                const int slot = (g64 & 56) | ((g64 ^ prow) & 7);
                lds[prow*512 + slot*8 + e] = bf16bits(v);
            }
        }
    }
    __syncthreads();

    // ---- epilogue 2: head GEMM M=128,N=64,K=512; wave wv -> rows wv*16..+15
    f32x4 acc2[4];
#pragma unroll
    for (int j = 0; j < 4; ++j) acc2[j] = (f32x4){0.f,0.f,0.f,0.f};
    const int hrow = wv*16 + l15;
#pragma unroll
    for (int k0 = 0; k0 < 16; ++k0) {
        const int g64 = k0*4 + lg;
        const int slot = (g64 & 56) | ((g64 ^ hrow) & 7);
        short8 a2 = *(const short8*)&lds[hrow*512 + slot*8];
#pragma unroll
        for (int j = 0; j < 4; ++j) {
            short8 b2 = *(const short8*)&Wc2[(size_t)(j*16 + l15)*NC + k0*32 + lg*8];
            acc2[j] = __builtin_amdgcn_mfma_f32_16x16x32_bf16(a2, b2, acc2[j], 0, 0, 0);
        }
    }
    __syncthreads();

    // ---- epilogue 3: stash head outputs to sm[128][65] f32
    float* sm = (float*)lds;
    const int crow0 = wv*16 + lg*4;
#pragma unroll
    for (int j = 0; j < 4; ++j)
#pragma unroll
        for (int r = 0; r < 4; ++r)
            sm[(crow0 + r)*65 + j*16 + l15] = acc2[j][r];
    __syncthreads();

    // ---- epilogue 4: anchor decode, 128 pos x 9 anchors = 1152 items
    for (int item = tid; item < 1152; item += 512) {
        int pl = item / 9, a = item - pl*9;
        int p = pbase + pl;
        int b = p >> 12, h = (p >> 6) & 63, w = p & 63;
        float c0 = sm[pl*65 + a*2 + 0] + cls_b[a*2 + 0];
        float c1 = sm[pl*65 + a*2 + 1] + cls_b[a*2 + 1];
        float r0 = sm[pl*65 + 18 + a*4 + 0] + reg_b[a*4 + 0];
        float r1 = sm[pl*65 + 18 + a*4 + 1] + reg_b[a*4 + 1];
        float r2 = sm[pl*65 + 18 + a*4 + 2] + reg_b[a*4 + 2];
        float r3 = sm[pl*65 + 18 + a*4 + 3] + reg_b[a*4 + 3];
        float aw = AW_T[a], ah = AH_T[a];
        float ax = 8.f + 16.f*w, ay = 8.f + 16.f*h;
        float px = ax + r0*aw,  py = ay + r1*ah;
        float pw = aw*__expf(r2), ph = ah*__expf(r3);
        float imw = (float)img[b*2 + 0], imh = (float)img[b*2 + 1];
        float x1 = fminf(fmaxf(px - 0.5f*pw, 0.f), imw);
        float y1 = fminf(fmaxf(py - 0.5f*ph, 0.f), imh);
        float x2 = fminf(fmaxf(px + 0.5f*pw, 0.f), imw);
        float y2 = fminf(fmaxf(py + 0.5f*ph, 0.f), imh);
        int ag = (h*64 + w)*9 + a;
        float4* prop = (float4*)(out + PROP_OFF + ((size_t)b*A_PER_B + ag)*4);
        *prop = make_float4(x1, y1, x2, y2);
        float2* cs = (float2*)(out + CLS_OFF + ((size_t)b*A_PER_B + ag)*2);
        *cs = make_float2(c0, c1);
    }
}

extern "C" void kernel_launch(void* const* d_in, const int* in_sizes, int n_in,
                              void* d_out, int out_size, void* d_ws, size_t ws_size,
                              hipStream_t stream) {
    const float* x      = (const float*)d_in[0];
    const int*   img    = (const int*)  d_in[1];
    const float* conv_w = (const float*)d_in[2];
    const float* conv_b = (const float*)d_in[3];
    const float* cls_w  = (const float*)d_in[4];
    const float* cls_b  = (const float*)d_in[5];
    const float* reg_w  = (const float*)d_in[6];
    const float* reg_b  = (const float*)d_in[7];
    float* out = (float*)d_out;

    short* Xp  = (short*)d_ws;
    short* Wr  = Xp  + XP_ELEMS;
    short* Wc2 = Wr  + WR_ELEMS;

    prep_misc<<<936, 256, 0, stream>>>(cls_w, reg_w, Wc2, Xp, out);
    prep_input<<<dim3(64,8,8), 256, 0, stream>>>(x, Xp);
    prep_w <<<512, 256, 0, stream>>>(conv_w, Wr);

    hipFuncSetAttribute((const void*)conv_fused,
                        hipFuncAttributeMaxDynamicSharedMemorySize, 131072);
    conv_fused<<<256, 512, 131072, stream>>>(Xp, Wr, conv_b, Wc2,
                                             cls_b, reg_b, img, out);
}